// Round 1
// baseline (77.057 us; speedup 1.0000x reference)
//
#include <hip/hip_runtime.h>
#include <cmath>

constexpr int B_ = 2, H_ = 8, N_ = 2048, DK_ = 64, DV_ = 64;
constexpr int BH_ = B_ * H_;      // 16
constexpr int C_ = 64;            // chunk size
constexpr int NC_ = N_ / C_;      // 32 chunks per (b,h)
constexpr int NCH_ = BH_ * NC_;   // 512 chunks total

// ---------------------------------------------------------------------------
// Kernel 1: per-row coefficients from omask.
// qc[i] = omask[i,0] / sqrt(sum_j omask[i,j]);  kc[i] = 1 / omask[i,0]
// One wave (64 lanes) per row of 2048 floats; float4 coalesced loads.
// ---------------------------------------------------------------------------
__global__ __launch_bounds__(256) void coef_kernel(const float* __restrict__ om,
                                                   float* __restrict__ qc,
                                                   float* __restrict__ kc) {
  int row = blockIdx.x * 4 + (threadIdx.x >> 6);   // 0 .. BH_*N_-1
  int lane = threadIdx.x & 63;
  const float* r = om + (size_t)row * N_;
  float s = 0.f;
#pragma unroll
  for (int kk = 0; kk < N_ / 256; ++kk) {          // 8 iterations
    float4 v4 = *(const float4*)(r + kk * 256 + lane * 4);
    s += (v4.x + v4.y) + (v4.z + v4.w);
  }
#pragma unroll
  for (int off = 32; off > 0; off >>= 1) s += __shfl_xor(s, off, 64);
  if (lane == 0) {
    float o0 = r[0];
    qc[row] = o0 / sqrtf(s);
    kc[row] = 1.0f / o0;
  }
}

// ---------------------------------------------------------------------------
// Kernel 2: per-chunk sums  ksum[dk] = sum_r kbar[r][dk],
//                           kv[dk][dv] = sum_r kbar[r][dk]*v[r][dv]
// One block per chunk; k_bar and v staged in LDS; 4x4 outer-product/thread.
// ---------------------------------------------------------------------------
__global__ __launch_bounds__(256) void chunksum_kernel(const float* __restrict__ kg,
                                                       const float* __restrict__ vg,
                                                       const float* __restrict__ kc,
                                                       float* __restrict__ ksum,
                                                       float* __restrict__ kvsum) {
  __shared__ float kb[C_][DK_];
  __shared__ float vs[C_][DV_];
  int chunk = blockIdx.x;
  int bh = chunk / NC_, ci = chunk - bh * NC_;
  int r0 = ci * C_;
  size_t gbase = ((size_t)bh * N_ + r0) * DK_;
  int t = threadIdx.x;
#pragma unroll
  for (int p = 0; p < 4; ++p) {
    int f = t + p * 256;                 // float4 index within chunk (0..1023)
    int row = f >> 4, col = (f & 15) * 4;
    float sc = kc[bh * N_ + r0 + row];
    float4 k4 = *(const float4*)(kg + gbase + (size_t)f * 4);
    k4.x *= sc; k4.y *= sc; k4.z *= sc; k4.w *= sc;
    *(float4*)&kb[row][col] = k4;
    *(float4*)&vs[row][col] = *(const float4*)(vg + gbase + (size_t)f * 4);
  }
  __syncthreads();
  int dk0 = (t & 15) * 4, dv0 = (t >> 4) * 4;
  float acc[4][4] = {};
  float ks[4] = {};
  for (int r = 0; r < C_; ++r) {
    float4 k4 = *(const float4*)&kb[r][dk0];
    float4 v4 = *(const float4*)&vs[r][dv0];
    float ka[4] = {k4.x, k4.y, k4.z, k4.w};
    float va[4] = {v4.x, v4.y, v4.z, v4.w};
#pragma unroll
    for (int i = 0; i < 4; ++i) {
      ks[i] += ka[i];
#pragma unroll
      for (int j = 0; j < 4; ++j) acc[i][j] += ka[i] * va[j];
    }
  }
  float* kvc = kvsum + (size_t)chunk * (DK_ * DV_);
#pragma unroll
  for (int i = 0; i < 4; ++i) {
    float4 w = make_float4(acc[i][0], acc[i][1], acc[i][2], acc[i][3]);
    *(float4*)(kvc + (size_t)(dk0 + i) * DV_ + dv0) = w;
  }
  if (t < 16) {
#pragma unroll
    for (int i = 0; i < 4; ++i) ksum[(size_t)chunk * DK_ + dk0 + i] = ks[i];
  }
}

// ---------------------------------------------------------------------------
// Kernel 3: exclusive prefix over chunks (per bh) of kv state + k sums.
// Thread-per-element, 32 sequential chunk steps.
// ---------------------------------------------------------------------------
__global__ __launch_bounds__(256) void scan_kernel(float* __restrict__ ksum,
                                                   float* __restrict__ kvsum) {
  constexpr int PER = DK_ * DV_ + DK_;   // 4160 elements per bh
  int idx = blockIdx.x * 256 + threadIdx.x;
  if (idx >= BH_ * PER) return;
  int bh = idx / PER, e = idx - bh * PER;
  float run = 0.f;
  if (e < DK_ * DV_) {
    float* p = kvsum + (size_t)bh * NC_ * (DK_ * DV_) + e;
    for (int ci = 0; ci < NC_; ++ci) {
      float tv = p[(size_t)ci * (DK_ * DV_)];
      p[(size_t)ci * (DK_ * DV_)] = run;
      run += tv;
    }
  } else {
    float* p = ksum + (size_t)bh * NC_ * DK_ + (e - DK_ * DV_);
    for (int ci = 0; ci < NC_; ++ci) {
      float tv = p[(size_t)ci * DK_];
      p[(size_t)ci * DK_] = run;
      run += tv;
    }
  }
}

// ---------------------------------------------------------------------------
// Kernel 4: outputs for one chunk.
//   O[i,c] = ( qbar[i]·Dpre[:,c] + sum_{j<=i in chunk} S[i,j] v[j,c] ) / P[i]
//   P[i]   = max(|qbar[i]·Tpre + rowsum_causal(S[i,:])|, 1)
// LDS: qbT (a-major), kbT (a-major, later reused as transposed S tile), v.
// ---------------------------------------------------------------------------
__global__ __launch_bounds__(256) void out_kernel(const float* __restrict__ qg,
                                                  const float* __restrict__ kg,
                                                  const float* __restrict__ vg,
                                                  const float* __restrict__ qc,
                                                  const float* __restrict__ kc,
                                                  const float* __restrict__ ksum,
                                                  const float* __restrict__ kvsum,
                                                  float* __restrict__ outg) {
  __shared__ float qbT[DK_][C_];   // [a][i]
  __shared__ float kbT[DK_][C_];   // [a][j]; reused as St[j][i] later
  __shared__ float vs[C_][DV_];    // [j][c]
  int chunk = blockIdx.x;
  int bh = chunk / NC_, ci = chunk - bh * NC_;
  int r0 = ci * C_;
  size_t gbase = ((size_t)bh * N_ + r0) * DK_;
  int t = threadIdx.x;
  {
    int i = t & 63;            // row within chunk (lane)
    int apart = t >> 6;        // which 16-wide a-slice this wave stages
    float qsc = qc[bh * N_ + r0 + i];
    float ksc = kc[bh * N_ + r0 + i];
#pragma unroll
    for (int u = 0; u < 4; ++u) {
      int a0 = apart * 16 + u * 4;
      float4 q4 = *(const float4*)(qg + gbase + (size_t)i * DK_ + a0);
      float4 k4 = *(const float4*)(kg + gbase + (size_t)i * DK_ + a0);
      qbT[a0 + 0][i] = q4.x * qsc; qbT[a0 + 1][i] = q4.y * qsc;
      qbT[a0 + 2][i] = q4.z * qsc; qbT[a0 + 3][i] = q4.w * qsc;
      kbT[a0 + 0][i] = k4.x * ksc; kbT[a0 + 1][i] = k4.y * ksc;
      kbT[a0 + 2][i] = k4.z * ksc; kbT[a0 + 3][i] = k4.w * ksc;
    }
#pragma unroll
    for (int p = 0; p < 4; ++p) {
      int f = t + p * 256;
      int row = f >> 4, col = (f & 15) * 4;
      *(float4*)&vs[row][col] = *(const float4*)(vg + gbase + (size_t)f * 4);
    }
  }
  __syncthreads();

  // Phase A: S tile (causal), 4x4 per thread.  i0 from (t&15) so the
  // transposed St write is only ~8-way conflicted (once per chunk, cheap).
  int i0 = (t & 15) * 4, j0 = (t >> 4) * 4;
  float acc[4][4] = {};
  for (int a = 0; a < DK_; ++a) {
    float4 q4 = *(const float4*)&qbT[a][i0];
    float4 k4 = *(const float4*)&kbT[a][j0];
    float qa[4] = {q4.x, q4.y, q4.z, q4.w};
    float kk[4] = {k4.x, k4.y, k4.z, k4.w};
#pragma unroll
    for (int ii = 0; ii < 4; ++ii)
#pragma unroll
      for (int jj = 0; jj < 4; ++jj) acc[ii][jj] += qa[ii] * kk[jj];
  }
  __syncthreads();                 // all reads of kbT done
  float (*St)[C_] = kbT;           // reuse kbT storage for transposed S
#pragma unroll
  for (int jj = 0; jj < 4; ++jj) {
    int j = j0 + jj;
    float4 w;
    w.x = (j <= i0 + 0) ? acc[0][jj] : 0.f;
    w.y = (j <= i0 + 1) ? acc[1][jj] : 0.f;
    w.z = (j <= i0 + 2) ? acc[2][jj] : 0.f;
    w.w = (j <= i0 + 3) ? acc[3][jj] : 0.f;
    *(float4*)&St[j][i0] = w;
  }
  __syncthreads();

  // Phase B: O = qb·Dpre + S·V ; P = qb·Tpre + rowsum(S)
  {
    int bi0 = (t >> 4) * 4, c0 = (t & 15) * 4;
    const float* kvp = kvsum + (size_t)chunk * (DK_ * DV_);
    const float* tp = ksum + (size_t)chunk * DK_;
    float o[4][4] = {};
    float pp[4] = {};
    for (int a = 0; a < DK_; ++a) {
      float4 q4 = *(const float4*)&qbT[a][bi0];
      float4 d4 = *(const float4*)(kvp + (size_t)a * DV_ + c0);
      float tv = tp[a];
      float qa[4] = {q4.x, q4.y, q4.z, q4.w};
      float da[4] = {d4.x, d4.y, d4.z, d4.w};
#pragma unroll
      for (int ii = 0; ii < 4; ++ii) {
        pp[ii] += qa[ii] * tv;
#pragma unroll
        for (int cc = 0; cc < 4; ++cc) o[ii][cc] += qa[ii] * da[cc];
      }
    }
    for (int j = 0; j < C_; ++j) {
      float4 s4 = *(const float4*)&St[j][bi0];
      float4 v4 = *(const float4*)&vs[j][c0];
      float sa[4] = {s4.x, s4.y, s4.z, s4.w};
      float va[4] = {v4.x, v4.y, v4.z, v4.w};
#pragma unroll
      for (int ii = 0; ii < 4; ++ii) {
        pp[ii] += sa[ii];
#pragma unroll
        for (int cc = 0; cc < 4; ++cc) o[ii][cc] += sa[ii] * va[cc];
      }
    }
    float* ob = outg + ((size_t)bh * N_ + r0) * DV_;
#pragma unroll
    for (int ii = 0; ii < 4; ++ii) {
      float P = fmaxf(fabsf(pp[ii]), 1.0f);
      float inv = 1.0f / P;
      float4 w = make_float4(o[ii][0] * inv, o[ii][1] * inv,
                             o[ii][2] * inv, o[ii][3] * inv);
      *(float4*)(ob + (size_t)(bi0 + ii) * DV_ + c0) = w;
    }
  }
}

// ---------------------------------------------------------------------------
extern "C" void kernel_launch(void* const* d_in, const int* in_sizes, int n_in,
                              void* d_out, int out_size, void* d_ws, size_t ws_size,
                              hipStream_t stream) {
  const float* q = (const float*)d_in[0];
  const float* k = (const float*)d_in[1];
  const float* v = (const float*)d_in[2];
  const float* om = (const float*)d_in[3];
  float* out = (float*)d_out;

  float* ws = (float*)d_ws;
  float* qc = ws;                          // BH_*N_      = 32768
  float* kc = qc + BH_ * N_;               // BH_*N_      = 32768
  float* ksum = kc + BH_ * N_;             // NCH_*DK_    = 32768
  float* kv = ksum + (size_t)NCH_ * DK_;   // NCH_*DK_*DV_ = 2,097,152

  coef_kernel<<<BH_ * N_ / 4, 256, 0, stream>>>(om, qc, kc);
  chunksum_kernel<<<NCH_, 256, 0, stream>>>(k, v, kc, ksum, kv);
  constexpr int SCAN_TOTAL = BH_ * (DK_ * DV_ + DK_);
  scan_kernel<<<(SCAN_TOTAL + 255) / 256, 256, 0, stream>>>(ksum, kv);
  out_kernel<<<NCH_, 256, 0, stream>>>(q, k, v, qc, kc, ksum, kv, out);
}